// Round 1
// baseline (2148.069 us; speedup 1.0000x reference)
//
#include <hip/hip_runtime.h>
#include <hip/hip_bf16.h>
#include <math.h>

#define BB  64
#define CC  512
#define NN  4
#define KK  1024
#define DD  128
#define HW  1024
#define PP  65536

// d_out layout (float32, concatenated in return order)
#define OFF_DIFF 33554432UL
#define OFF_ARG  33554433UL
#define OFF_PPL  33816577UL

// d_ws layout (bytes)
//   0      : hist  u32[4096]
//   16384  : dsum  double
//   16392  : wlcnt u32
//   16416  : enorm f32[4096]
//   32800  : wl    int2[wlcap]
#define WS_HIST   0
#define WS_DSUM   16384
#define WS_WLCNT  16392
#define WS_ENORM  16416
#define WS_WL     32800

#define DELTA 0.0625f   // margin threshold for fp64 re-check

__global__ __launch_bounds__(256) void vq_enorm(const float* __restrict__ embed,
                                                float* __restrict__ enorm) {
    int nk = blockIdx.x * 256 + threadIdx.x;        // 16 blocks * 256 = 4096
    int n = nk >> 10, k = nk & 1023;
    const float* e = embed + (size_t)n * (DD * KK) + k;
    float s = 0.f;
    #pragma unroll 4
    for (int d = 0; d < DD; ++d) { float v = e[(size_t)d * KK]; s = fmaf(v, v, s); }
    enorm[nk] = s;
}

__global__ __launch_bounds__(256) void vq_main(const float* __restrict__ x,
                                               const float* __restrict__ embed,
                                               const float* __restrict__ enorm,
                                               float* __restrict__ out,
                                               unsigned* __restrict__ hist,
                                               double* __restrict__ dsum,
                                               unsigned* __restrict__ wlcnt,
                                               int2* __restrict__ wl, int wlcap) {
    __shared__ float zs[DD][64];
    __shared__ float es[DD][64];
    __shared__ float ens[KK];
    __shared__ int   idx_s[NN][64];
    __shared__ float wsum[4];

    const int t   = threadIdx.x;
    const int blk = blockIdx.x;                 // 1024 blocks: 16 per batch
    const int b   = blk >> 4;
    const int hw0 = (blk & 15) << 6;            // 64 consecutive (h,w) positions
    const float* xb = x + (size_t)b * (CC * HW) + hw0;

    const int tk = t & 15;                      // k-group: 16 consecutive lanes share a p-group
    const int tp = t >> 4;                      // p-group (16 groups of 4 positions)

    for (int n = 0; n < NN; ++n) {
        __syncthreads();                        // zs/ens reuse guard
        for (int i = t; i < DD * 64; i += 256) {
            int d = i >> 6, p = i & 63;
            zs[d][p] = xb[(size_t)(n * DD + d) * HW + p];
        }
        for (int i = t; i < KK; i += 256) ens[i] = enorm[n * KK + i];

        float b1[4], b2[4]; int k1[4];
        #pragma unroll
        for (int i = 0; i < 4; ++i) { b1[i] = INFINITY; b2[i] = INFINITY; k1[i] = 0; }

        for (int kt = 0; kt < 16; ++kt) {
            __syncthreads();                    // es reuse guard (also covers zs staging at kt=0)
            for (int i = t; i < DD * 64; i += 256) {
                int d = i >> 6, kk = i & 63;
                es[d][kk] = embed[(size_t)(n * DD + d) * KK + kt * 64 + kk];
            }
            __syncthreads();

            float acc[4][4];
            #pragma unroll
            for (int i = 0; i < 4; ++i)
                #pragma unroll
                for (int j = 0; j < 4; ++j) acc[i][j] = 0.f;

            #pragma unroll 2
            for (int d = 0; d < DD; ++d) {
                float4 zv = *(const float4*)&zs[d][tp * 4];
                float4 ev = *(const float4*)&es[d][tk * 4];
                float za[4] = {zv.x, zv.y, zv.z, zv.w};
                float ea[4] = {ev.x, ev.y, ev.z, ev.w};
                #pragma unroll
                for (int i = 0; i < 4; ++i)
                    #pragma unroll
                    for (int j = 0; j < 4; ++j)
                        acc[i][j] = fmaf(za[i], ea[j], acc[i][j]);
            }
            // running top-2 per owned position; k ascending => first-min tie rule
            #pragma unroll
            for (int j = 0; j < 4; ++j) {
                int kg = kt * 64 + tk * 4 + j;
                float e2 = ens[kg];
                #pragma unroll
                for (int i = 0; i < 4; ++i) {
                    float dv = fmaf(-2.f, acc[i][j], e2);   // znorm dropped: shift-invariant
                    if (dv < b1[i]) { b2[i] = b1[i]; b1[i] = dv; k1[i] = kg; }
                    else if (dv < b2[i]) { b2[i] = dv; }
                }
            }
        }
        // merge top-2 across the 16 consecutive lanes sharing tp (same wave)
        #pragma unroll
        for (int off = 1; off < 16; off <<= 1) {
            #pragma unroll
            for (int i = 0; i < 4; ++i) {
                float ob1 = __shfl_xor(b1[i], off);
                int   ok1 = __shfl_xor(k1[i], off);
                float ob2 = __shfl_xor(b2[i], off);
                float nb2 = fminf(b2[i], ob2);
                if (ob1 < b1[i] || (ob1 == b1[i] && ok1 < k1[i])) {
                    b2[i] = fminf(nb2, b1[i]);
                    b1[i] = ob1; k1[i] = ok1;
                } else {
                    b2[i] = fminf(nb2, ob1);
                }
            }
        }
        if (tk == 0) {
            #pragma unroll
            for (int i = 0; i < 4; ++i) {
                int p = tp * 4 + i;
                idx_s[n][p] = k1[i];
                atomicAdd(&hist[n * KK + k1[i]], 1u);
                if (b2[i] - b1[i] < DELTA) {           // near-tie -> fp64 re-check
                    unsigned pos = atomicAdd(wlcnt, 1u);
                    if ((int)pos < wlcap) wl[pos] = make_int2(b * HW + hw0 + p, n);
                }
            }
        }
    }
    __syncthreads();

    // argmin output (as float)
    {
        int n = t >> 6, p = t & 63;
        out[OFF_ARG + (size_t)b * (NN * HW) + (size_t)n * HW + hw0 + p] = (float)idx_s[n][p];
    }

    // z_q gather + diff partial
    float dacc = 0.f;
    {
        int p  = t & 63;
        int cc = t >> 6;
        for (int c0 = 0; c0 < CC; c0 += 4) {
            int c = c0 + cc;
            int n = c >> 7, d = c & 127;
            int k = idx_s[n][p];
            float q  = embed[(size_t)(n * DD + d) * KK + k];
            float zv = xb[(size_t)c * HW + p];
            out[(size_t)(b * CC + c) * HW + hw0 + p] = q;
            float df = q - zv;
            dacc = fmaf(df, df, dacc);
        }
    }
    #pragma unroll
    for (int off = 32; off > 0; off >>= 1) dacc += __shfl_down(dacc, off);
    if ((t & 63) == 0) wsum[t >> 6] = dacc;
    __syncthreads();
    if (t == 0) {
        double s = (double)wsum[0] + (double)wsum[1] + (double)wsum[2] + (double)wsum[3];
        atomicAdd(dsum, s);
    }
}

__global__ __launch_bounds__(256) void vq_refine(const float* __restrict__ x,
                                                 const float* __restrict__ embed,
                                                 float* __restrict__ out,
                                                 unsigned* __restrict__ hist,
                                                 const unsigned* __restrict__ wlcnt,
                                                 const int2* __restrict__ wl, int wlcap) {
    __shared__ double zd[DD];
    __shared__ double sval[256];
    __shared__ int    sidx[256];
    const int t = threadIdx.x;
    unsigned wc = *wlcnt;
    int nitems = (int)(wc < (unsigned)wlcap ? wc : (unsigned)wlcap);

    for (int it = blockIdx.x; it < nitems; it += gridDim.x) {
        int2 item = wl[it];
        int p = item.x, n = item.y;
        int b = p >> 10, hw = p & 1023;
        __syncthreads();                                   // zd reuse guard
        if (t < DD) zd[t] = (double)x[((size_t)b * CC + n * DD + t) * HW + hw];
        __syncthreads();

        double lb = INFINITY; int lk = 0;
        for (int j = 0; j < 4; ++j) {
            int k = t * 4 + j;
            const float* ek = embed + (size_t)n * (DD * KK) + k;
            double s = 0.0, e2 = 0.0;
            for (int d = 0; d < DD; ++d) {
                double ev = (double)ek[(size_t)d * KK];
                s  = fma(zd[d], ev, s);
                e2 = fma(ev, ev, e2);
            }
            double dist = e2 - 2.0 * s;                    // shift-invariant argmin
            if (dist < lb) { lb = dist; lk = k; }
        }
        sval[t] = lb; sidx[t] = lk;
        __syncthreads();
        for (int off = 128; off > 0; off >>= 1) {
            if (t < off) {
                double ov = sval[t + off]; int oi = sidx[t + off];
                if (ov < sval[t] || (ov == sval[t] && oi < sidx[t])) { sval[t] = ov; sidx[t] = oi; }
            }
            __syncthreads();
        }
        if (t == 0) {
            size_t slot = OFF_ARG + (size_t)b * (NN * HW) + (size_t)n * HW + hw;
            int oldk = (int)out[slot];
            int newk = sidx[0];
            if (newk != oldk) {
                out[slot] = (float)newk;
                atomicSub(&hist[n * KK + oldk], 1u);
                atomicAdd(&hist[n * KK + newk], 1u);
            }
        }
    }
}

__global__ __launch_bounds__(256) void vq_final(const unsigned* __restrict__ hist,
                                                const double* __restrict__ dsum,
                                                float* __restrict__ out) {
    __shared__ double red[256];
    __shared__ double hn[NN];
    const int t = threadIdx.x;
    for (int n = 0; n < NN; ++n) {
        double acc = 0.0;
        for (int k = t; k < KK; k += 256) {
            double pr = (double)hist[n * KK + k] / (double)PP;
            acc += pr * log(pr + 1e-10);
        }
        red[t] = acc;
        __syncthreads();
        for (int off = 128; off > 0; off >>= 1) {
            if (t < off) red[t] += red[t + off];
            __syncthreads();
        }
        if (t == 0) hn[n] = red[0];
        __syncthreads();
    }
    if (t == 0) {
        double ppl = 0.0;
        for (int n = 0; n < NN; ++n) ppl += exp(-hn[n]);
        out[OFF_PPL]  = (float)(ppl * 0.25);
        out[OFF_DIFF] = (float)(*dsum / (double)((size_t)BB * CC * HW));
    }
}

extern "C" void kernel_launch(void* const* d_in, const int* in_sizes, int n_in,
                              void* d_out, int out_size, void* d_ws, size_t ws_size,
                              hipStream_t stream) {
    const float* x     = (const float*)d_in[0];
    const float* embed = (const float*)d_in[1];
    float* out = (float*)d_out;
    char*  ws  = (char*)d_ws;

    unsigned* hist   = (unsigned*)(ws + WS_HIST);
    double*   dsum   = (double*)  (ws + WS_DSUM);
    unsigned* wlcnt  = (unsigned*)(ws + WS_WLCNT);
    float*    enorm  = (float*)   (ws + WS_ENORM);
    int2*     wl     = (int2*)    (ws + WS_WL);

    long long cap = ((long long)ws_size - WS_WL) / (long long)sizeof(int2);
    int wlcap = cap < 0 ? 0 : (cap > 65536 ? 65536 : (int)cap);

    hipMemsetAsync(d_ws, 0, 16400, stream);                 // hist + dsum + wlcnt
    vq_enorm <<<16,   256, 0, stream>>>(embed, enorm);
    vq_main  <<<1024, 256, 0, stream>>>(x, embed, enorm, out, hist, dsum, wlcnt, wl, wlcap);
    vq_refine<<<128,  256, 0, stream>>>(x, embed, out, hist, wlcnt, wl, wlcap);
    vq_final <<<1,    256, 0, stream>>>(hist, dsum, out);
}

// Round 2
// 1605.336 us; speedup vs baseline: 1.3381x; 1.3381x over previous
//
#include <hip/hip_runtime.h>
#include <hip/hip_bf16.h>
#include <math.h>

#define BB  64
#define CC  512
#define NN  4
#define KK  1024
#define DD  128
#define HW  1024
#define PP  65536

// d_out layout (float32, concatenated in return order)
#define OFF_DIFF 33554432UL
#define OFF_ARG  33554433UL
#define OFF_PPL  33816577UL

// d_ws layout (bytes)
#define WS_HIST   0
#define WS_DSUM   16384
#define WS_WLCNT  16392
#define WS_ENORM  16416
#define WS_WL     32800

#define DELTA 0.0625f   // near-tie margin -> fp64 re-check

typedef short s16x8 __attribute__((ext_vector_type(8)));
typedef float f32x4 __attribute__((ext_vector_type(4)));

__device__ __forceinline__ unsigned short f2bf(float f) {
    unsigned u = __builtin_bit_cast(unsigned, f);
    u += 0x7fffu + ((u >> 16) & 1u);
    return (unsigned short)(u >> 16);
}
__device__ __forceinline__ float bf2f(unsigned short h) {
    unsigned u = ((unsigned)h) << 16;
    return __builtin_bit_cast(float, u);
}
// swizzled LDS byte offset for [row][128 bf16] tiles: XOR 16B-slot index with row&15
__device__ __forceinline__ int swz(int row, int dbyte) {
    return (row * 256 + dbyte) ^ ((row & 15) << 4);
}

__global__ __launch_bounds__(256) void vq_enorm(const float* __restrict__ embed,
                                                float* __restrict__ enorm) {
    int nk = blockIdx.x * 256 + threadIdx.x;
    int n = nk >> 10, k = nk & 1023;
    const float* e = embed + (size_t)n * (DD * KK) + k;
    float s = 0.f;
    #pragma unroll 4
    for (int d = 0; d < DD; ++d) { float v = e[(size_t)d * KK]; s = fmaf(v, v, s); }
    enorm[nk] = s;
}

__global__ __launch_bounds__(256, 2) void vq_main(const float* __restrict__ x,
                                                  const float* __restrict__ embed,
                                                  const float* __restrict__ enorm,
                                                  float* __restrict__ out,
                                                  unsigned* __restrict__ hist,
                                                  double* __restrict__ dsum,
                                                  unsigned* __restrict__ wlcnt,
                                                  int2* __restrict__ wl, int wlcap) {
    __shared__ __attribute__((aligned(16))) unsigned short zs_hi[64 * 128];
    __shared__ __attribute__((aligned(16))) unsigned short zs_lo[64 * 128];
    __shared__ __attribute__((aligned(16))) unsigned short et_hi[64 * 128];
    __shared__ __attribute__((aligned(16))) unsigned short et_lo[64 * 128];
    __shared__ int   idx_s[NN][64];
    __shared__ float red_b1[4][64], red_b2[4][64];
    __shared__ int   red_k1[4][64];
    __shared__ float wsum[4];

    const int t   = threadIdx.x;
    const int blk = blockIdx.x;                 // 1024 blocks: 16 per batch
    const int b   = blk >> 4;
    const int hw0 = (blk & 15) << 6;
    const float* xb = x + (size_t)b * (CC * HW) + hw0;
    const int w  = t >> 6;                      // wave 0..3  (owns k-strip w*16 per tile)
    const int l  = t & 63;
    const int tk = l & 15;
    const int lg = l >> 4;

    for (int n = 0; n < NN; ++n) {
        __syncthreads();                        // zs / red / idx reuse guard
        // ---- stage z -> zs_hi/zs_lo: rows p=l, wave w covers d in [32w,32w+32)
        #pragma unroll
        for (int j = 0; j < 4; ++j) {
            int d0 = (w * 4 + j) * 8;
            s16x8 vh, vl;
            #pragma unroll
            for (int r = 0; r < 8; ++r) {
                float f = xb[(size_t)(n * DD + d0 + r) * HW + l];
                unsigned short h = f2bf(f);
                vh[r] = (short)h;
                vl[r] = (short)f2bf(f - bf2f(h));
            }
            int off = swz(l, d0 * 2);
            *(s16x8*)((char*)zs_hi + off) = vh;
            *(s16x8*)((char*)zs_lo + off) = vl;
        }
        __syncthreads();

        // ---- A-fragments held in registers for the whole n
        s16x8 a_hi[4][4], a_lo[4][4];           // [mf][dstep]
        #pragma unroll
        for (int mf = 0; mf < 4; ++mf)
            #pragma unroll
            for (int ds = 0; ds < 4; ++ds) {
                int off = swz(mf * 16 + tk, (ds * 32 + lg * 8) * 2);
                a_hi[mf][ds] = *(const s16x8*)((const char*)zs_hi + off);
                a_lo[mf][ds] = *(const s16x8*)((const char*)zs_lo + off);
            }

        float b1v[16], b2v[16]; int k1v[16];    // rows: r = mf*4+i -> p = mf*16+lg*4+i
        #pragma unroll
        for (int r = 0; r < 16; ++r) { b1v[r] = INFINITY; b2v[r] = INFINITY; k1v[r] = 0; }

        for (int kt = 0; kt < 16; ++kt) {
            const int k0 = kt * 64;
            __syncthreads();                    // et overwrite guard
            // ---- stage e-tile (64 codes) -> et_hi/et_lo, transposed [k][d]
            #pragma unroll
            for (int j = 0; j < 4; ++j) {
                int d0 = (w * 4 + j) * 8;
                s16x8 vh, vl;
                #pragma unroll
                for (int r = 0; r < 8; ++r) {
                    float f = embed[(size_t)(n * DD + d0 + r) * KK + k0 + l];
                    unsigned short h = f2bf(f);
                    vh[r] = (short)h;
                    vl[r] = (short)f2bf(f - bf2f(h));
                }
                int off = swz(l, d0 * 2);
                *(s16x8*)((char*)et_hi + off) = vh;
                *(s16x8*)((char*)et_lo + off) = vl;
            }
            __syncthreads();                    // et ready

            const int kcol = k0 + w * 16 + tk;  // this lane's C column
            const float e2 = enorm[n * KK + kcol];

            f32x4 acc[4] = {f32x4{0,0,0,0}, f32x4{0,0,0,0}, f32x4{0,0,0,0}, f32x4{0,0,0,0}};
            #pragma unroll
            for (int ds = 0; ds < 4; ++ds) {
                int off = swz(w * 16 + tk, (ds * 32 + lg * 8) * 2);
                s16x8 bh = *(const s16x8*)((const char*)et_hi + off);
                s16x8 bl = *(const s16x8*)((const char*)et_lo + off);
                #pragma unroll
                for (int mf = 0; mf < 4; ++mf) {
                    acc[mf] = __builtin_amdgcn_mfma_f32_16x16x32_bf16(a_hi[mf][ds], bh, acc[mf], 0, 0, 0);
                    acc[mf] = __builtin_amdgcn_mfma_f32_16x16x32_bf16(a_lo[mf][ds], bh, acc[mf], 0, 0, 0);
                    acc[mf] = __builtin_amdgcn_mfma_f32_16x16x32_bf16(a_hi[mf][ds], bl, acc[mf], 0, 0, 0);
                }
            }
            // ---- running top-2 (lane sees one k per tile; kt ascending => first-min rule)
            #pragma unroll
            for (int mf = 0; mf < 4; ++mf)
                #pragma unroll
                for (int i = 0; i < 4; ++i) {
                    float dv = fmaf(-2.f, acc[mf][i], e2);
                    int r = mf * 4 + i;
                    if (dv < b1v[r]) { b2v[r] = b1v[r]; b1v[r] = dv; k1v[r] = kcol; }
                    else             { b2v[r] = fminf(b2v[r], dv); }
                }
        }

        // ---- merge across the 16 lane-columns of the wave
        #pragma unroll
        for (int off = 1; off < 16; off <<= 1) {
            #pragma unroll
            for (int r = 0; r < 16; ++r) {
                float ob1 = __shfl_xor(b1v[r], off);
                float ob2 = __shfl_xor(b2v[r], off);
                int   ok1 = __shfl_xor(k1v[r], off);
                float nb2 = fminf(b2v[r], ob2);
                if (ob1 < b1v[r] || (ob1 == b1v[r] && ok1 < k1v[r])) {
                    b2v[r] = fminf(nb2, b1v[r]); b1v[r] = ob1; k1v[r] = ok1;
                } else {
                    b2v[r] = fminf(nb2, ob1);
                }
            }
        }
        if (tk == 0) {
            #pragma unroll
            for (int mf = 0; mf < 4; ++mf)
                #pragma unroll
                for (int i = 0; i < 4; ++i) {
                    int p = mf * 16 + lg * 4 + i, r = mf * 4 + i;
                    red_b1[w][p] = b1v[r]; red_b2[w][p] = b2v[r]; red_k1[w][p] = k1v[r];
                }
        }
        __syncthreads();                        // red ready
        if (t < 64) {                           // merge the 4 waves' k-quarters
            int p = t;
            float m1 = red_b1[0][p], m2 = red_b2[0][p]; int mk = red_k1[0][p];
            #pragma unroll
            for (int ww = 1; ww < 4; ++ww) {
                float ob1 = red_b1[ww][p], ob2 = red_b2[ww][p]; int ok = red_k1[ww][p];
                float nb2 = fminf(m2, ob2);
                if (ob1 < m1 || (ob1 == m1 && ok < mk)) { m2 = fminf(nb2, m1); m1 = ob1; mk = ok; }
                else                                    { m2 = fminf(nb2, ob1); }
            }
            idx_s[n][p] = mk;
            atomicAdd(&hist[n * KK + mk], 1u);
            if (m2 - m1 < DELTA) {              // near-tie -> exact fp64 re-check
                unsigned pos = atomicAdd(wlcnt, 1u);
                if ((int)pos < wlcap) wl[pos] = make_int2(b * HW + hw0 + p, n);
            }
        }
    }
    __syncthreads();

    // ---- argmin output (as float)
    {
        int n2 = t >> 6, p = t & 63;
        out[OFF_ARG + (size_t)b * (NN * HW) + (size_t)n2 * HW + hw0 + p] = (float)idx_s[n2][p];
    }

    // ---- z_q gather + diff partial
    float dacc = 0.f;
    {
        int p  = t & 63;
        int cc = t >> 6;
        for (int c0 = 0; c0 < CC; c0 += 4) {
            int c = c0 + cc;
            int n2 = c >> 7, d = c & 127;
            int k = idx_s[n2][p];
            float q  = embed[(size_t)(n2 * DD + d) * KK + k];
            float zv = xb[(size_t)c * HW + p];
            out[(size_t)(b * CC + c) * HW + hw0 + p] = q;
            float df = q - zv;
            dacc = fmaf(df, df, dacc);
        }
    }
    #pragma unroll
    for (int off = 32; off > 0; off >>= 1) dacc += __shfl_down(dacc, off);
    if ((t & 63) == 0) wsum[t >> 6] = dacc;
    __syncthreads();
    if (t == 0) {
        double s = (double)wsum[0] + (double)wsum[1] + (double)wsum[2] + (double)wsum[3];
        atomicAdd(dsum, s);
    }
}

__global__ __launch_bounds__(256) void vq_refine(const float* __restrict__ x,
                                                 const float* __restrict__ embed,
                                                 float* __restrict__ out,
                                                 unsigned* __restrict__ hist,
                                                 const unsigned* __restrict__ wlcnt,
                                                 const int2* __restrict__ wl, int wlcap) {
    __shared__ double zd[DD];
    __shared__ double sval[256];
    __shared__ int    sidx[256];
    const int t = threadIdx.x;
    unsigned wc = *wlcnt;
    int nitems = (int)(wc < (unsigned)wlcap ? wc : (unsigned)wlcap);

    for (int it = blockIdx.x; it < nitems; it += gridDim.x) {
        int2 item = wl[it];
        int p = item.x, n = item.y;
        int b = p >> 10, hw = p & 1023;
        __syncthreads();
        if (t < DD) zd[t] = (double)x[((size_t)b * CC + n * DD + t) * HW + hw];
        __syncthreads();

        double lb = INFINITY; int lk = 0;
        for (int j = 0; j < 4; ++j) {
            int k = t * 4 + j;
            const float* ek = embed + (size_t)n * (DD * KK) + k;
            double s = 0.0, e2 = 0.0;
            for (int d = 0; d < DD; ++d) {
                double ev = (double)ek[(size_t)d * KK];
                s  = fma(zd[d], ev, s);
                e2 = fma(ev, ev, e2);
            }
            double dist = e2 - 2.0 * s;
            if (dist < lb) { lb = dist; lk = k; }
        }
        sval[t] = lb; sidx[t] = lk;
        __syncthreads();
        for (int off = 128; off > 0; off >>= 1) {
            if (t < off) {
                double ov = sval[t + off]; int oi = sidx[t + off];
                if (ov < sval[t] || (ov == sval[t] && oi < sidx[t])) { sval[t] = ov; sidx[t] = oi; }
            }
            __syncthreads();
        }
        if (t == 0) {
            size_t slot = OFF_ARG + (size_t)b * (NN * HW) + (size_t)n * HW + hw;
            int oldk = (int)out[slot];
            int newk = sidx[0];
            if (newk != oldk) {
                out[slot] = (float)newk;
                atomicSub(&hist[n * KK + oldk], 1u);
                atomicAdd(&hist[n * KK + newk], 1u);
            }
        }
    }
}

__global__ __launch_bounds__(256) void vq_final(const unsigned* __restrict__ hist,
                                                const double* __restrict__ dsum,
                                                float* __restrict__ out) {
    __shared__ double red[256];
    __shared__ double hn[NN];
    const int t = threadIdx.x;
    for (int n = 0; n < NN; ++n) {
        double acc = 0.0;
        for (int k = t; k < KK; k += 256) {
            double pr = (double)hist[n * KK + k] / (double)PP;
            acc += pr * log(pr + 1e-10);
        }
        red[t] = acc;
        __syncthreads();
        for (int off = 128; off > 0; off >>= 1) {
            if (t < off) red[t] += red[t + off];
            __syncthreads();
        }
        if (t == 0) hn[n] = red[0];
        __syncthreads();
    }
    if (t == 0) {
        double ppl = 0.0;
        for (int n = 0; n < NN; ++n) ppl += exp(-hn[n]);
        out[OFF_PPL]  = (float)(ppl * 0.25);
        out[OFF_DIFF] = (float)(*dsum / (double)((size_t)BB * CC * HW));
    }
}

extern "C" void kernel_launch(void* const* d_in, const int* in_sizes, int n_in,
                              void* d_out, int out_size, void* d_ws, size_t ws_size,
                              hipStream_t stream) {
    const float* x     = (const float*)d_in[0];
    const float* embed = (const float*)d_in[1];
    float* out = (float*)d_out;
    char*  ws  = (char*)d_ws;

    unsigned* hist   = (unsigned*)(ws + WS_HIST);
    double*   dsum   = (double*)  (ws + WS_DSUM);
    unsigned* wlcnt  = (unsigned*)(ws + WS_WLCNT);
    float*    enorm  = (float*)   (ws + WS_ENORM);
    int2*     wl     = (int2*)    (ws + WS_WL);

    long long cap = ((long long)ws_size - WS_WL) / (long long)sizeof(int2);
    int wlcap = cap < 0 ? 0 : (cap > 65536 ? 65536 : (int)cap);

    hipMemsetAsync(d_ws, 0, 16400, stream);                 // hist + dsum + wlcnt
    vq_enorm <<<16,   256, 0, stream>>>(embed, enorm);
    vq_main  <<<1024, 256, 0, stream>>>(x, embed, enorm, out, hist, dsum, wlcnt, wl, wlcap);
    vq_refine<<<128,  256, 0, stream>>>(x, embed, out, hist, wlcnt, wl, wlcap);
    vq_final <<<1,    256, 0, stream>>>(hist, dsum, out);
}

// Round 3
// 821.967 us; speedup vs baseline: 2.6133x; 1.9530x over previous
//
#include <hip/hip_runtime.h>
#include <hip/hip_bf16.h>
#include <math.h>

#define BB  64
#define CC  512
#define NN  4
#define KK  1024
#define DD  128
#define HW  1024
#define PP  65536

// d_out layout (float32, concatenated in return order)
#define OFF_DIFF 33554432UL
#define OFF_ARG  33554433UL
#define OFF_PPL  33816577UL

// d_ws layout (bytes)
#define WS_HIST   0
#define WS_DSUM   16384
#define WS_WLCNT  16392
#define WS_ENORM  16416
#define WS_EBF    32800                 // 64 tiles * 32768 B = 2 MiB (pre-swizzled bf16 hi/lo)
#define WS_WL     (32800 + 64*32768)

#define DELTA 0.0625f   // near-tie margin -> fp64 re-check

typedef short s16x8 __attribute__((ext_vector_type(8)));
typedef float f32x4 __attribute__((ext_vector_type(4)));

__device__ __forceinline__ unsigned short f2bf(float f) {
    unsigned u = __builtin_bit_cast(unsigned, f);
    u += 0x7fffu + ((u >> 16) & 1u);
    return (unsigned short)(u >> 16);
}
__device__ __forceinline__ float bf2f(unsigned short h) {
    unsigned u = ((unsigned)h) << 16;
    return __builtin_bit_cast(float, u);
}
// swizzled byte offset for [row][128 bf16] tiles: XOR 16B-slot with row&15
__device__ __forceinline__ int swz(int row, int dbyte) {
    return (row * 256 + dbyte) ^ ((row & 15) << 4);
}
__device__ __forceinline__ void gl2lds16(const void* g, void* l) {
    __builtin_amdgcn_global_load_lds(
        (const __attribute__((address_space(1))) unsigned int*)g,
        (__attribute__((address_space(3))) unsigned int*)l, 16, 0, 0);
}

// ---- prep: embed -> pre-swizzled bf16 hi/lo tiles + enorm ------------------
// grid 64 = n(4) x kt(16); tile = [hi 16KB | lo 16KB], row=k(64), col=d(128)
__global__ __launch_bounds__(256) void vq_prep(const float* __restrict__ embed,
                                               char* __restrict__ ebf,
                                               float* __restrict__ enorm) {
    __shared__ float sred[4][64];
    const int e = blockIdx.x, n = e >> 4, kt = e & 15, k0 = kt * 64;
    const int t = threadIdx.x, kr = t & 63, dc = t >> 6;   // 4 d-chunks of 32
    const float* src = embed + ((size_t)n * DD + dc * 32) * KK + k0 + kr;
    char* tile = ebf + (size_t)e * 32768;
    float fv[32];
    #pragma unroll
    for (int r = 0; r < 32; ++r) fv[r] = src[(size_t)r * KK];
    float s = 0.f;
    #pragma unroll
    for (int j = 0; j < 4; ++j) {
        s16x8 vh, vl;
        #pragma unroll
        for (int r = 0; r < 8; ++r) {
            float f = fv[j * 8 + r];
            unsigned short h = f2bf(f);
            vh[r] = (short)h;
            vl[r] = (short)f2bf(f - bf2f(h));
            s = fmaf(f, f, s);
        }
        int o = swz(kr, (dc * 32 + j * 8) * 2);
        *(s16x8*)(tile + o)         = vh;
        *(s16x8*)(tile + 16384 + o) = vl;
    }
    sred[dc][kr] = s;
    __syncthreads();
    if (t < 64) enorm[n * KK + k0 + t] = (sred[0][t] + sred[1][t]) + (sred[2][t] + sred[3][t]);
}

// ---- main ------------------------------------------------------------------
__global__ __launch_bounds__(512, 2) void vq_main(const float* __restrict__ x,
                                                  const float* __restrict__ embed,
                                                  const char* __restrict__ ebf,
                                                  const float* __restrict__ enormg,
                                                  float* __restrict__ out,
                                                  unsigned* __restrict__ hist,
                                                  double* __restrict__ dsum,
                                                  unsigned* __restrict__ wlcnt,
                                                  int2* __restrict__ wl, int wlcap) {
    __shared__ __attribute__((aligned(16))) unsigned short zs_hi[128 * 128];  // 32KB
    __shared__ __attribute__((aligned(16))) unsigned short zs_lo[128 * 128];  // 32KB
    __shared__ __attribute__((aligned(16))) unsigned short ebuf[2][2][64 * 128]; // 64KB
    __shared__ int   idx_s[NN][128];
    __shared__ float red_b1[4][128], red_b2[4][128];
    __shared__ int   red_k1[4][128];
    __shared__ float wsum[8];

    const int t   = threadIdx.x;
    const int blk = blockIdx.x;                 // 512 blocks: 8 per batch
    const int b   = blk >> 3;
    const int hw0 = (blk & 7) << 7;             // 128 consecutive positions
    const int w  = t >> 6, l = t & 63;
    const int h  = w >> 2;                      // p-half (64 rows)
    const int s  = w & 3;                       // k-strip (16 cols per 64-tile)
    const int tk = l & 15, lg = l >> 4;

    char* ebase = (char*)&ebuf[0][0][0];
    auto STAGE = [&](int bs, int nn, int kk) {
        const char* src = ebf + ((size_t)(nn * 16 + kk)) * 32768 + w * 4096 + l * 16;
        char* dst = ebase + bs * 32768 + w * 4096 + l * 16;
        #pragma unroll
        for (int j = 0; j < 4; ++j) gl2lds16(src + j * 1024, dst + j * 1024);
    };

    int bsel = 0;
    float znacc = 0.f, sumb1 = 0.f;

    for (int n = 0; n < NN; ++n) {
        __syncthreads();                        // zs / red / idx reuse guard
        // ---- stage z (fp32 -> bf16 hi/lo, swizzled): row p, thread owns 32 d
        {
            const int p = t & 127, dchunk = t >> 7;
            const float* xp = x + ((size_t)b * CC + n * DD + dchunk * 32) * HW + hw0 + p;
            float fv[32];
            #pragma unroll
            for (int r = 0; r < 32; ++r) fv[r] = xp[(size_t)r * HW];
            #pragma unroll
            for (int j = 0; j < 4; ++j) {
                s16x8 vh, vl;
                #pragma unroll
                for (int r = 0; r < 8; ++r) {
                    float f = fv[j * 8 + r];
                    unsigned short hh = f2bf(f);
                    vh[r] = (short)hh;
                    vl[r] = (short)f2bf(f - bf2f(hh));
                    znacc = fmaf(f, f, znacc);
                }
                int o = swz(p, (dchunk * 32 + j * 8) * 2);
                *(s16x8*)((char*)zs_hi + o) = vh;
                *(s16x8*)((char*)zs_lo + o) = vl;
            }
        }
        if (n == 0) STAGE(0, 0, 0);
        __syncthreads();                        // zs + ebuf[0] ready (vmcnt drained)

        // ---- A-fragments in registers for the whole n
        s16x8 a_hi[4][4], a_lo[4][4];
        #pragma unroll
        for (int mf = 0; mf < 4; ++mf)
            #pragma unroll
            for (int ds = 0; ds < 4; ++ds) {
                int o = swz(h * 64 + mf * 16 + tk, (ds * 32 + lg * 8) * 2);
                a_hi[mf][ds] = *(const s16x8*)((const char*)zs_hi + o);
                a_lo[mf][ds] = *(const s16x8*)((const char*)zs_lo + o);
            }

        float b1v[16], b2v[16]; int k1v[16];
        #pragma unroll
        for (int r = 0; r < 16; ++r) { b1v[r] = INFINITY; b2v[r] = INFINITY; k1v[r] = 0; }

        #pragma unroll 2
        for (int kt = 0; kt < 16; ++kt) {
            if (kt < 15)      STAGE(bsel ^ 1, n, kt + 1);
            else if (n < 3)   STAGE(bsel ^ 1, n + 1, 0);

            const int kcol = kt * 64 + s * 16 + tk;
            const float e2 = enormg[n * KK + kcol];

            f32x4 acc[4] = {f32x4{0,0,0,0}, f32x4{0,0,0,0}, f32x4{0,0,0,0}, f32x4{0,0,0,0}};
            #pragma unroll
            for (int ds = 0; ds < 4; ++ds) {
                int o = swz(s * 16 + tk, (ds * 32 + lg * 8) * 2);
                s16x8 bh = *(const s16x8*)(ebase + bsel * 32768 + o);
                s16x8 bl = *(const s16x8*)(ebase + bsel * 32768 + 16384 + o);
                #pragma unroll
                for (int mf = 0; mf < 4; ++mf) {
                    acc[mf] = __builtin_amdgcn_mfma_f32_16x16x32_bf16(a_hi[mf][ds], bh, acc[mf], 0, 0, 0);
                    acc[mf] = __builtin_amdgcn_mfma_f32_16x16x32_bf16(a_lo[mf][ds], bh, acc[mf], 0, 0, 0);
                    acc[mf] = __builtin_amdgcn_mfma_f32_16x16x32_bf16(a_hi[mf][ds], bl, acc[mf], 0, 0, 0);
                }
            }
            // top-2 update: one k per lane per kt, ascending kt => first-min rule
            #pragma unroll
            for (int mf = 0; mf < 4; ++mf)
                #pragma unroll
                for (int i = 0; i < 4; ++i) {
                    float dv = fmaf(-2.f, acc[mf][i], e2);
                    int r = mf * 4 + i;
                    if (dv < b1v[r]) { b2v[r] = b1v[r]; b1v[r] = dv; k1v[r] = kcol; }
                    else             { b2v[r] = fminf(b2v[r], dv); }
                }
            __syncthreads();                    // buf swap guard
            bsel ^= 1;
        }

        // ---- merge across the 16 lane-columns (tk) of the wave
        #pragma unroll
        for (int off = 1; off < 16; off <<= 1) {
            #pragma unroll
            for (int r = 0; r < 16; ++r) {
                float ob1 = __shfl_xor(b1v[r], off);
                float ob2 = __shfl_xor(b2v[r], off);
                int   ok1 = __shfl_xor(k1v[r], off);
                float nb2 = fminf(b2v[r], ob2);
                if (ob1 < b1v[r] || (ob1 == b1v[r] && ok1 < k1v[r])) {
                    b2v[r] = fminf(nb2, b1v[r]); b1v[r] = ob1; k1v[r] = ok1;
                } else {
                    b2v[r] = fminf(nb2, ob1);
                }
            }
        }
        if (tk == 0) {
            #pragma unroll
            for (int mf = 0; mf < 4; ++mf)
                #pragma unroll
                for (int i = 0; i < 4; ++i) {
                    int p = h * 64 + mf * 16 + lg * 4 + i, r = mf * 4 + i;
                    red_b1[s][p] = b1v[r]; red_b2[s][p] = b2v[r]; red_k1[s][p] = k1v[r];
                }
        }
        __syncthreads();
        if (t < 128) {                          // merge the 4 k-strips
            int p = t;
            float m1 = red_b1[0][p], m2 = red_b2[0][p]; int mk = red_k1[0][p];
            #pragma unroll
            for (int ss = 1; ss < 4; ++ss) {
                float ob1 = red_b1[ss][p], ob2 = red_b2[ss][p]; int ok = red_k1[ss][p];
                float nb2 = fminf(m2, ob2);
                if (ob1 < m1 || (ob1 == m1 && ok < mk)) { m2 = fminf(nb2, m1); m1 = ob1; mk = ok; }
                else                                    { m2 = fminf(nb2, ob1); }
            }
            idx_s[n][p] = mk;
            atomicAdd(&hist[n * KK + mk], 1u);
            sumb1 += m1;                        // diff: ||z-q||^2 = znorm + (enorm - 2 z.e)
            if (m2 - m1 < DELTA) {
                unsigned pos = atomicAdd(wlcnt, 1u);
                if ((int)pos < wlcap) wl[pos] = make_int2(b * HW + hw0 + p, n);
            }
        }
    }

    // ---- diff partial reduce
    {
        float tot = znacc + sumb1;
        #pragma unroll
        for (int off = 32; off > 0; off >>= 1) tot += __shfl_down(tot, off);
        if (l == 0) wsum[w] = tot;
        __syncthreads();                        // also guards idx_s for epilogue
        if (t == 0) {
            double sd = 0.0;
            #pragma unroll
            for (int ww = 0; ww < 8; ++ww) sd += (double)wsum[ww];
            atomicAdd(dsum, sd);
        }
    }

    // ---- argmin output (as float)
    {
        int n2 = t >> 7, p = t & 127;
        out[OFF_ARG + (size_t)b * (NN * HW) + (size_t)n2 * HW + hw0 + p] = (float)idx_s[n2][p];
    }

    // ---- z_q gather (embed L2-resident) + coalesced float2 stores
    {
        const int pb = (t & 63) * 2;            // even p; lane-contiguous pairs
        const int cc = t >> 6;                  // 0..7
        #pragma unroll
        for (int n2 = 0; n2 < 4; ++n2) {
            int ka = idx_s[n2][pb], kb = idx_s[n2][pb + 1];
            #pragma unroll 4
            for (int jj = 0; jj < 16; ++jj) {
                int c = n2 * 128 + cc + 8 * jj;
                float q0 = embed[(size_t)c * KK + ka];
                float q1 = embed[(size_t)c * KK + kb];
                *(float2*)&out[((size_t)b * CC + c) * HW + hw0 + pb] = make_float2(q0, q1);
            }
        }
    }
}

// ---- fp64 exact re-check of near-ties (also fixes hist) --------------------
__global__ __launch_bounds__(256) void vq_refine(const float* __restrict__ x,
                                                 const float* __restrict__ embed,
                                                 float* __restrict__ out,
                                                 unsigned* __restrict__ hist,
                                                 const unsigned* __restrict__ wlcnt,
                                                 const int2* __restrict__ wl, int wlcap) {
    __shared__ double zd[DD];
    __shared__ double sval[256];
    __shared__ int    sidx[256];
    const int t = threadIdx.x;
    unsigned wc = *wlcnt;
    int nitems = (int)(wc < (unsigned)wlcap ? wc : (unsigned)wlcap);

    for (int it = blockIdx.x; it < nitems; it += gridDim.x) {
        int2 item = wl[it];
        int p = item.x, n = item.y;
        int b = p >> 10, hw = p & 1023;
        __syncthreads();
        if (t < DD) zd[t] = (double)x[((size_t)b * CC + n * DD + t) * HW + hw];
        __syncthreads();

        double lb = INFINITY; int lk = 0;
        for (int j = 0; j < 4; ++j) {
            int k = t * 4 + j;
            const float* ek = embed + (size_t)n * (DD * KK) + k;
            double ss = 0.0, e2 = 0.0;
            for (int d = 0; d < DD; ++d) {
                double ev = (double)ek[(size_t)d * KK];
                ss = fma(zd[d], ev, ss);
                e2 = fma(ev, ev, e2);
            }
            double dist = e2 - 2.0 * ss;
            if (dist < lb) { lb = dist; lk = k; }
        }
        sval[t] = lb; sidx[t] = lk;
        __syncthreads();
        for (int off = 128; off > 0; off >>= 1) {
            if (t < off) {
                double ov = sval[t + off]; int oi = sidx[t + off];
                if (ov < sval[t] || (ov == sval[t] && oi < sidx[t])) { sval[t] = ov; sidx[t] = oi; }
            }
            __syncthreads();
        }
        if (t == 0) {
            size_t slot = OFF_ARG + (size_t)b * (NN * HW) + (size_t)n * HW + hw;
            int oldk = (int)out[slot];
            int newk = sidx[0];
            if (newk != oldk) {
                out[slot] = (float)newk;
                atomicSub(&hist[n * KK + oldk], 1u);
                atomicAdd(&hist[n * KK + newk], 1u);
            }
        }
    }
}

__global__ __launch_bounds__(256) void vq_final(const unsigned* __restrict__ hist,
                                                const double* __restrict__ dsum,
                                                float* __restrict__ out) {
    __shared__ double red[256];
    __shared__ double hn[NN];
    const int t = threadIdx.x;
    for (int n = 0; n < NN; ++n) {
        double acc = 0.0;
        for (int k = t; k < KK; k += 256) {
            double pr = (double)hist[n * KK + k] / (double)PP;
            acc += pr * log(pr + 1e-10);
        }
        red[t] = acc;
        __syncthreads();
        for (int off = 128; off > 0; off >>= 1) {
            if (t < off) red[t] += red[t + off];
            __syncthreads();
        }
        if (t == 0) hn[n] = red[0];
        __syncthreads();
    }
    if (t == 0) {
        double ppl = 0.0;
        for (int n = 0; n < NN; ++n) ppl += exp(-hn[n]);
        out[OFF_PPL]  = (float)(ppl * 0.25);
        out[OFF_DIFF] = (float)(*dsum / (double)((size_t)BB * CC * HW));
    }
}

extern "C" void kernel_launch(void* const* d_in, const int* in_sizes, int n_in,
                              void* d_out, int out_size, void* d_ws, size_t ws_size,
                              hipStream_t stream) {
    const float* x     = (const float*)d_in[0];
    const float* embed = (const float*)d_in[1];
    float* out = (float*)d_out;
    char*  ws  = (char*)d_ws;

    unsigned* hist   = (unsigned*)(ws + WS_HIST);
    double*   dsum   = (double*)  (ws + WS_DSUM);
    unsigned* wlcnt  = (unsigned*)(ws + WS_WLCNT);
    float*    enorm  = (float*)   (ws + WS_ENORM);
    char*     ebf    = ws + WS_EBF;
    int2*     wl     = (int2*)    (ws + WS_WL);

    long long cap = ((long long)ws_size - WS_WL) / (long long)sizeof(int2);
    int wlcap = cap < 0 ? 0 : (cap > 65536 ? 65536 : (int)cap);

    hipMemsetAsync(d_ws, 0, 16400, stream);                 // hist + dsum + wlcnt
    vq_prep  <<<64,   256, 0, stream>>>(embed, ebf, enorm);
    vq_main  <<<512,  512, 0, stream>>>(x, embed, ebf, enorm, out, hist, dsum, wlcnt, wl, wlcap);
    vq_refine<<<2048, 256, 0, stream>>>(x, embed, out, hist, wlcnt, wl, wlcap);
    vq_final <<<1,    256, 0, stream>>>(hist, dsum, out);
}

// Round 4
// 505.297 us; speedup vs baseline: 4.2511x; 1.6267x over previous
//
#include <hip/hip_runtime.h>
#include <hip/hip_bf16.h>
#include <math.h>

#define BB  64
#define CC  512
#define NN  4
#define KK  1024
#define DD  128
#define HW  1024
#define PP  65536

// d_out layout (float32, concatenated in return order)
#define OFF_DIFF 33554432UL
#define OFF_ARG  33554433UL
#define OFF_PPL  33816577UL

// d_ws layout (bytes)
#define WS_HIST   0
#define WS_DSUM   16384
#define WS_WLCNT  16392
#define WS_ENORM  16416
#define WS_EBF    32800                         // 64 tiles * 32768 B = 2 MiB (pre-swizzled bf16 hi/lo)
#define WS_EMBT   (32800 + 64*32768)            // fp32 embed_t[n][k][d], 2 MiB
#define WS_WL     (WS_EMBT + NN*KK*DD*4)

#define DELTA 0.0625f   // near-tie margin -> fp64 re-check

typedef short s16x8 __attribute__((ext_vector_type(8)));
typedef float f32x4 __attribute__((ext_vector_type(4)));

__device__ __forceinline__ unsigned short f2bf(float f) {
    unsigned u = __builtin_bit_cast(unsigned, f);
    u += 0x7fffu + ((u >> 16) & 1u);
    return (unsigned short)(u >> 16);
}
__device__ __forceinline__ float bf2f(unsigned short h) {
    unsigned u = ((unsigned)h) << 16;
    return __builtin_bit_cast(float, u);
}
// swizzled byte offset for [row][128 bf16] tiles: XOR 16B-slot with row&15
__device__ __forceinline__ int swz(int row, int dbyte) {
    return (row * 256 + dbyte) ^ ((row & 15) << 4);
}
__device__ __forceinline__ void gl2lds16(const void* g, void* l) {
    __builtin_amdgcn_global_load_lds(
        (const __attribute__((address_space(1))) unsigned int*)g,
        (__attribute__((address_space(3))) unsigned int*)l, 16, 0, 0);
}

// ---- prep: embed -> pre-swizzled bf16 hi/lo tiles + fp32 embed_t + enorm ---
// grid 64 = n(4) x kt(16); tile = [hi 16KB | lo 16KB], row=k(64), col=d(128)
__global__ __launch_bounds__(256) void vq_prep(const float* __restrict__ embed,
                                               char* __restrict__ ebf,
                                               float* __restrict__ embt,
                                               float* __restrict__ enorm) {
    __shared__ float sred[4][64];
    const int e = blockIdx.x, n = e >> 4, kt = e & 15, k0 = kt * 64;
    const int t = threadIdx.x, kr = t & 63, dc = t >> 6;   // 4 d-chunks of 32
    const float* src = embed + ((size_t)n * DD + dc * 32) * KK + k0 + kr;
    char* tile = ebf + (size_t)e * 32768;
    float fv[32];
    #pragma unroll
    for (int r = 0; r < 32; ++r) fv[r] = src[(size_t)r * KK];
    float s = 0.f;
    #pragma unroll
    for (int j = 0; j < 4; ++j) {
        s16x8 vh, vl;
        #pragma unroll
        for (int r = 0; r < 8; ++r) {
            float f = fv[j * 8 + r];
            unsigned short h = f2bf(f);
            vh[r] = (short)h;
            vl[r] = (short)f2bf(f - bf2f(h));
            s = fmaf(f, f, s);
        }
        int o = swz(kr, (dc * 32 + j * 8) * 2);
        *(s16x8*)(tile + o)         = vh;
        *(s16x8*)(tile + 16384 + o) = vl;
    }
    // fp32 transposed codebook row: embt[(n*KK + k)][d]
    {
        float* drow = embt + ((size_t)n * KK + k0 + kr) * DD + dc * 32;
        #pragma unroll
        for (int j = 0; j < 8; ++j)
            *(float4*)(drow + j * 4) = make_float4(fv[j*4], fv[j*4+1], fv[j*4+2], fv[j*4+3]);
    }
    sred[dc][kr] = s;
    __syncthreads();
    if (t < 64) enorm[n * KK + k0 + t] = (sred[0][t] + sred[1][t]) + (sred[2][t] + sred[3][t]);
}

// ---- main ------------------------------------------------------------------
// 8 waves = 4 p-quarters (32 rows) x 2 k-halves (32 of each 64-code tile)
__global__ __launch_bounds__(512, 2) void vq_main(const float* __restrict__ x,
                                                  const char* __restrict__ ebf,
                                                  const float* __restrict__ embt,
                                                  const float* __restrict__ enormg,
                                                  float* __restrict__ out,
                                                  unsigned* __restrict__ hist,
                                                  double* __restrict__ dsum,
                                                  unsigned* __restrict__ wlcnt,
                                                  int2* __restrict__ wl, int wlcap) {
    __shared__ __attribute__((aligned(16))) unsigned short zs_hi[128 * 128];  // 32KB
    __shared__ __attribute__((aligned(16))) unsigned short zs_lo[128 * 128];  // 32KB
    __shared__ __attribute__((aligned(16))) unsigned short ebuf[2][2][64 * 128]; // 64KB
    __shared__ int   idx_s[NN][128];
    __shared__ float red_b1[2][128], red_b2[2][128];
    __shared__ int   red_k1[2][128];
    __shared__ float wsum[8];

    const int t   = threadIdx.x;
    const int blk = blockIdx.x;                 // 512 blocks: 8 per batch
    const int b   = blk >> 3;
    const int hw0 = (blk & 7) << 7;             // 128 consecutive positions
    const int w  = t >> 6, l = t & 63;
    const int pq = w >> 1;                      // p-quarter (32 rows)
    const int ks = w & 1;                       // k-half (32 of 64 per tile)
    const int tk = l & 15, lg = l >> 4;

    char* ebase = (char*)&ebuf[0][0][0];
    auto STAGE = [&](int bs, int nn, int kk) {
        const char* src = ebf + ((size_t)(nn * 16 + kk)) * 32768 + w * 4096 + l * 16;
        char* dst = ebase + bs * 32768 + w * 4096 + l * 16;
        #pragma unroll
        for (int j = 0; j < 4; ++j) gl2lds16(src + j * 1024, dst + j * 1024);
    };

    int bsel = 0;
    float znacc = 0.f, sumb1 = 0.f;

    for (int n = 0; n < NN; ++n) {
        __syncthreads();                        // zs / red / idx reuse guard
        if (n == 0) STAGE(0, 0, 0);             // overlap with z staging
        // ---- stage z (fp32 -> bf16 hi/lo, swizzled): row p, thread owns 32 d
        {
            const int p = t & 127, dchunk = t >> 7;
            const float* xp = x + ((size_t)b * CC + n * DD + dchunk * 32) * HW + hw0 + p;
            float fv[32];
            #pragma unroll
            for (int r = 0; r < 32; ++r) fv[r] = xp[(size_t)r * HW];
            #pragma unroll
            for (int j = 0; j < 4; ++j) {
                s16x8 vh, vl;
                #pragma unroll
                for (int r = 0; r < 8; ++r) {
                    float f = fv[j * 8 + r];
                    unsigned short hh = f2bf(f);
                    vh[r] = (short)hh;
                    vl[r] = (short)f2bf(f - bf2f(hh));
                    znacc = fmaf(f, f, znacc);
                }
                int o = swz(p, (dchunk * 32 + j * 8) * 2);
                *(s16x8*)((char*)zs_hi + o) = vh;
                *(s16x8*)((char*)zs_lo + o) = vl;
            }
        }
        __syncthreads();                        // zs + ebuf ready (vmcnt drained)

        // ---- A-fragments in registers for the whole n (16 frags = 64 VGPR)
        s16x8 a_hi[2][4], a_lo[2][4];
        #pragma unroll
        for (int mf = 0; mf < 2; ++mf)
            #pragma unroll
            for (int ds = 0; ds < 4; ++ds) {
                int o = swz(pq * 32 + mf * 16 + tk, (ds * 32 + lg * 8) * 2);
                a_hi[mf][ds] = *(const s16x8*)((const char*)zs_hi + o);
                a_lo[mf][ds] = *(const s16x8*)((const char*)zs_lo + o);
            }

        float b1v[8], b2v[8]; int k1v[8];       // r = mf*4+i -> p = pq*32+mf*16+lg*4+i
        #pragma unroll
        for (int r = 0; r < 8; ++r) { b1v[r] = INFINITY; b2v[r] = INFINITY; k1v[r] = 0; }

        for (int kt = 0; kt < 16; ++kt) {
            if (kt < 15)      STAGE(bsel ^ 1, n, kt + 1);
            else if (n < 3)   STAGE(bsel ^ 1, n + 1, 0);

            const int kbase = kt * 64 + ks * 32;
            float e2v[2] = { enormg[n * KK + kbase + tk], enormg[n * KK + kbase + 16 + tk] };

            f32x4 acc[2][2] = {{f32x4{0,0,0,0}, f32x4{0,0,0,0}},
                               {f32x4{0,0,0,0}, f32x4{0,0,0,0}}};
            #pragma unroll
            for (int ds = 0; ds < 4; ++ds) {
                #pragma unroll
                for (int kt2 = 0; kt2 < 2; ++kt2) {
                    int o = swz(ks * 32 + kt2 * 16 + tk, (ds * 32 + lg * 8) * 2);
                    s16x8 bh = *(const s16x8*)(ebase + bsel * 32768 + o);
                    s16x8 bl = *(const s16x8*)(ebase + bsel * 32768 + 16384 + o);
                    #pragma unroll
                    for (int mf = 0; mf < 2; ++mf) {
                        acc[mf][kt2] = __builtin_amdgcn_mfma_f32_16x16x32_bf16(a_hi[mf][ds], bh, acc[mf][kt2], 0, 0, 0);
                        acc[mf][kt2] = __builtin_amdgcn_mfma_f32_16x16x32_bf16(a_lo[mf][ds], bh, acc[mf][kt2], 0, 0, 0);
                        acc[mf][kt2] = __builtin_amdgcn_mfma_f32_16x16x32_bf16(a_hi[mf][ds], bl, acc[mf][kt2], 0, 0, 0);
                    }
                }
            }
            // top-2: lane sees 2 k per kt, ascending (kt2 0 then 1) => first-min rule
            #pragma unroll
            for (int kt2 = 0; kt2 < 2; ++kt2) {
                const int kcol = kbase + kt2 * 16 + tk;
                const float e2 = e2v[kt2];
                #pragma unroll
                for (int mf = 0; mf < 2; ++mf)
                    #pragma unroll
                    for (int i = 0; i < 4; ++i) {
                        float dv = fmaf(-2.f, acc[mf][kt2][i], e2);
                        int r = mf * 4 + i;
                        if (dv < b1v[r]) { b2v[r] = b1v[r]; b1v[r] = dv; k1v[r] = kcol; }
                        else             { b2v[r] = fminf(b2v[r], dv); }
                    }
            }
            __syncthreads();                    // buf swap guard
            bsel ^= 1;
        }

        // ---- merge across the 16 lane-columns (tk) of the wave
        #pragma unroll
        for (int off = 1; off < 16; off <<= 1) {
            #pragma unroll
            for (int r = 0; r < 8; ++r) {
                float ob1 = __shfl_xor(b1v[r], off);
                float ob2 = __shfl_xor(b2v[r], off);
                int   ok1 = __shfl_xor(k1v[r], off);
                float nb2 = fminf(b2v[r], ob2);
                if (ob1 < b1v[r] || (ob1 == b1v[r] && ok1 < k1v[r])) {
                    b2v[r] = fminf(nb2, b1v[r]); b1v[r] = ob1; k1v[r] = ok1;
                } else {
                    b2v[r] = fminf(nb2, ob1);
                }
            }
        }
        if (tk == 0) {
            #pragma unroll
            for (int mf = 0; mf < 2; ++mf)
                #pragma unroll
                for (int i = 0; i < 4; ++i) {
                    int p = pq * 32 + mf * 16 + lg * 4 + i, r = mf * 4 + i;
                    red_b1[ks][p] = b1v[r]; red_b2[ks][p] = b2v[r]; red_k1[ks][p] = k1v[r];
                }
        }
        __syncthreads();
        if (t < 128) {                          // merge the 2 k-halves
            int p = t;
            float m1 = red_b1[0][p], m2 = red_b2[0][p]; int mk = red_k1[0][p];
            {
                float ob1 = red_b1[1][p], ob2 = red_b2[1][p]; int ok = red_k1[1][p];
                float nb2 = fminf(m2, ob2);
                if (ob1 < m1 || (ob1 == m1 && ok < mk)) { m2 = fminf(nb2, m1); m1 = ob1; mk = ok; }
                else                                    { m2 = fminf(nb2, ob1); }
            }
            idx_s[n][p] = mk;
            atomicAdd(&hist[n * KK + mk], 1u);
            sumb1 += m1;                        // diff: ||z-q||^2 = znorm + (enorm - 2 z.e)
            if (m2 - m1 < DELTA) {
                unsigned pos = atomicAdd(wlcnt, 1u);
                if ((int)pos < wlcap) wl[pos] = make_int2(b * HW + hw0 + p, n);
            }
        }
    }

    // ---- diff partial reduce
    {
        float tot = znacc + sumb1;
        #pragma unroll
        for (int off = 32; off > 0; off >>= 1) tot += __shfl_down(tot, off);
        if (l == 0) wsum[w] = tot;
        __syncthreads();                        // also guards idx_s for epilogue
        if (t == 0) {
            double sd = 0.0;
            #pragma unroll
            for (int ww = 0; ww < 8; ++ww) sd += (double)wsum[ww];
            atomicAdd(dsum, sd);
        }
    }

    // ---- argmin output (as float)
    {
        int n2 = t >> 7, p = t & 127;
        out[OFF_ARG + (size_t)b * (NN * HW) + (size_t)n2 * HW + hw0 + p] = (float)idx_s[n2][p];
    }

    // ---- z_q gather: contiguous embed_t rows (L1-friendly) + coalesced stores
    {
        const int p = t & 127, dchunk = t >> 7;
        #pragma unroll
        for (int n2 = 0; n2 < NN; ++n2) {
            int k = idx_s[n2][p];
            const float4* src = (const float4*)(embt + ((size_t)n2 * KK + k) * DD + dchunk * 32);
            const int c0 = n2 * 128 + dchunk * 32;
            #pragma unroll
            for (int r = 0; r < 8; ++r) {
                float4 q = src[r];
                out[((size_t)b * CC + c0 + r * 4 + 0) * HW + hw0 + p] = q.x;
                out[((size_t)b * CC + c0 + r * 4 + 1) * HW + hw0 + p] = q.y;
                out[((size_t)b * CC + c0 + r * 4 + 2) * HW + hw0 + p] = q.z;
                out[((size_t)b * CC + c0 + r * 4 + 3) * HW + hw0 + p] = q.w;
            }
        }
    }
}

// ---- fp64 exact re-check of near-ties (also fixes hist) --------------------
__global__ __launch_bounds__(256) void vq_refine(const float* __restrict__ x,
                                                 const float* __restrict__ embt,
                                                 float* __restrict__ out,
                                                 unsigned* __restrict__ hist,
                                                 const unsigned* __restrict__ wlcnt,
                                                 const int2* __restrict__ wl, int wlcap) {
    __shared__ double zd[DD];
    __shared__ double sval[256];
    __shared__ int    sidx[256];
    const int t = threadIdx.x;
    unsigned wc = *wlcnt;
    int nitems = (int)(wc < (unsigned)wlcap ? wc : (unsigned)wlcap);

    for (int it = blockIdx.x; it < nitems; it += gridDim.x) {
        int2 item = wl[it];
        int p = item.x, n = item.y;
        int b = p >> 10, hw = p & 1023;
        __syncthreads();
        if (t < DD) zd[t] = (double)x[((size_t)b * CC + n * DD + t) * HW + hw];
        __syncthreads();

        double lb = INFINITY; int lk = 0;
        for (int j = 0; j < 4; ++j) {
            int k = t * 4 + j;
            const float4* er = (const float4*)(embt + ((size_t)n * KK + k) * DD);
            double ss = 0.0, e2 = 0.0;
            #pragma unroll 8
            for (int r = 0; r < 32; ++r) {
                float4 v = er[r];
                double e0 = (double)v.x, e1 = (double)v.y, e2d = (double)v.z, e3 = (double)v.w;
                ss = fma(zd[r*4+0], e0, ss); e2 = fma(e0, e0, e2);
                ss = fma(zd[r*4+1], e1, ss); e2 = fma(e1, e1, e2);
                ss = fma(zd[r*4+2], e2d, ss); e2 = fma(e2d, e2d, e2);
                ss = fma(zd[r*4+3], e3, ss); e2 = fma(e3, e3, e2);
            }
            double dist = e2 - 2.0 * ss;
            if (dist < lb) { lb = dist; lk = k; }
        }
        sval[t] = lb; sidx[t] = lk;
        __syncthreads();
        for (int off = 128; off > 0; off >>= 1) {
            if (t < off) {
                double ov = sval[t + off]; int oi = sidx[t + off];
                if (ov < sval[t] || (ov == sval[t] && oi < sidx[t])) { sval[t] = ov; sidx[t] = oi; }
            }
            __syncthreads();
        }
        if (t == 0) {
            size_t slot = OFF_ARG + (size_t)b * (NN * HW) + (size_t)n * HW + hw;
            int oldk = (int)out[slot];
            int newk = sidx[0];
            if (newk != oldk) {
                out[slot] = (float)newk;
                atomicSub(&hist[n * KK + oldk], 1u);
                atomicAdd(&hist[n * KK + newk], 1u);
            }
        }
    }
}

__global__ __launch_bounds__(256) void vq_final(const unsigned* __restrict__ hist,
                                                const double* __restrict__ dsum,
                                                float* __restrict__ out) {
    __shared__ double red[256];
    __shared__ double hn[NN];
    const int t = threadIdx.x;
    for (int n = 0; n < NN; ++n) {
        double acc = 0.0;
        for (int k = t; k < KK; k += 256) {
            double pr = (double)hist[n * KK + k] / (double)PP;
            acc += pr * log(pr + 1e-10);
        }
        red[t] = acc;
        __syncthreads();
        for (int off = 128; off > 0; off >>= 1) {
            if (t < off) red[t] += red[t + off];
            __syncthreads();
        }
        if (t == 0) hn[n] = red[0];
        __syncthreads();
    }
    if (t == 0) {
        double ppl = 0.0;
        for (int n = 0; n < NN; ++n) ppl += exp(-hn[n]);
        out[OFF_PPL]  = (float)(ppl * 0.25);
        out[OFF_DIFF] = (float)(*dsum / (double)((size_t)BB * CC * HW));
    }
}

extern "C" void kernel_launch(void* const* d_in, const int* in_sizes, int n_in,
                              void* d_out, int out_size, void* d_ws, size_t ws_size,
                              hipStream_t stream) {
    const float* x     = (const float*)d_in[0];
    const float* embed = (const float*)d_in[1];
    float* out = (float*)d_out;
    char*  ws  = (char*)d_ws;

    unsigned* hist   = (unsigned*)(ws + WS_HIST);
    double*   dsum   = (double*)  (ws + WS_DSUM);
    unsigned* wlcnt  = (unsigned*)(ws + WS_WLCNT);
    float*    enorm  = (float*)   (ws + WS_ENORM);
    char*     ebf    = ws + WS_EBF;
    float*    embt   = (float*)   (ws + WS_EMBT);
    int2*     wl     = (int2*)    (ws + WS_WL);

    long long cap = ((long long)ws_size - WS_WL) / (long long)sizeof(int2);
    int wlcap = cap < 0 ? 0 : (cap > 65536 ? 65536 : (int)cap);

    hipMemsetAsync(d_ws, 0, 16400, stream);                 // hist + dsum + wlcnt
    vq_prep  <<<64,   256, 0, stream>>>(embed, ebf, embt, enorm);
    vq_main  <<<512,  512, 0, stream>>>(x, ebf, embt, enorm, out, hist, dsum, wlcnt, wl, wlcap);
    vq_refine<<<2048, 256, 0, stream>>>(x, embt, out, hist, wlcnt, wl, wlcap);
    vq_final <<<1,    256, 0, stream>>>(hist, dsum, out);
}